// Round 13
// baseline (81.731 us; speedup 1.0000x reference)
//
#include <hip/hip_runtime.h>
#include <hip/hip_bf16.h>
#include <math.h>

#define BB 8
#define LL 1024
#define DD 512
#define VV 64
#define KK 8

constexpr float INV_TEMP = 10.0f;   // 1/TEMP
constexpr float EPSF     = 1e-10f;

// ---------------- workspace float layout (NO atomics, NO memset) ------------
#define WS_DENP   0                        // den partials [8192][16]
#define WS_CLS    (8192*16)                // cls  {sum,cnt} x 2048
#define WS_EMP    (WS_CLS + 4096)          // emp  {sum,cnt} x 2048, slot = b*256+li
#define WS_CONTR  (WS_EMP + 4096)          // contr {sum,cnt} x 4096 (mat0:[0,2048))
#define WS_PTRROW (WS_CONTR + 8192)        // ptr per-row {sumd,cnt} x 8192

typedef __attribute__((ext_vector_type(8))) short  short8;
typedef __attribute__((ext_vector_type(4))) float  f32x4;

// ---------------- bool-dtype detection ----------------
// MUST be fed attention_mask: its first L entries are all-True by construction.
__device__ __forceinline__ int mask_mode(const void* att_raw) {
    const unsigned* w = (const unsigned*)att_raw;
    unsigned w0 = w[0];
    if (w0 == 0x01010101u) return 0;           // bool/uint8
    if (w0 == 0x3f800000u) return 2;           // float32
    if (w0 == 1u) return (w[1] == 0u) ? 3 : 1; // int64 : int32
    return 0;
}
__device__ __forceinline__ bool get_mask(const void* p, int idx, int mode) {
    if (mode == 0) return ((const unsigned char*)p)[idx] != 0;
    if (mode == 1) return ((const int*)p)[idx] != 0;
    if (mode == 3) return ((const unsigned*)p)[2*idx] != 0u;
    return ((const float*)p)[idx] != 0.0f;
}

__device__ __forceinline__ float wave_red_sum(float v) {
    #pragma unroll
    for (int off = 32; off; off >>= 1) v += __shfl_xor(v, off);
    return v;
}
__device__ __forceinline__ float wave_red_max(float v) {
    #pragma unroll
    for (int off = 32; off; off >>= 1) v = fmaxf(v, __shfl_xor(v, off));
    return v;
}

__device__ __forceinline__ short bfb(float f) {
    __hip_bfloat16 h = __float2bfloat16(f);
    union { __hip_bfloat16 h; short u; } c; c.h = h; return c.u;
}

#define ST 40            // LDS row stride in shorts (80 bytes)

// ================= mega: contr x8 | den x4 | rest x4 | cls x4 per group ======
// 512 groups x 20 blocks. den/rest use b = bid&7 (XCD round-robin affinity);
// parity of g walks the (b, tile) space exactly once. contr loads are
// non-temporal so the 128MB stream doesn't evict den's box/tag L2 bands.
__global__ __launch_bounds__(256, 8) void k_mega(
        const float* __restrict__ box,     const float* __restrict__ tag,
        const float* __restrict__ logits,  const int* __restrict__ tok,
        const int* __restrict__ bidx,      const float* __restrict__ emptyp,
        const float* __restrict__ row_sim, const float* __restrict__ col_sim,
        const float* __restrict__ row_coef,const float* __restrict__ col_coef,
        const void* __restrict__ dtm_raw,  const void* __restrict__ att_raw,
        float* __restrict__ ws) {
    __shared__ short As[64 * ST];
    __shared__ short Bs[64 * ST];

    int bid = blockIdx.x;
    int g   = bid / 20;
    int r   = bid - g * 20;
    int tid  = threadIdx.x;
    int lane = tid & 63;
    int wv   = tid >> 6;

    if (r < 8) {
        // ---------------- span contrastive (nt loads, shift-invariant) -------
        int cidx = g * 8 + r;              // 0..4095
        int gw   = cidx * 4 + wv;
        int mat  = gw >> 13;
        int row  = gw & 8191;
        int j    = row & 1023;
        const f32x4* sim  = (const f32x4*)((mat ? col_sim  : row_sim)  + (size_t)row * LL);
        const f32x4* coef = (const f32x4*)((mat ? col_coef : row_coef) + (size_t)row * LL);

        f32x4 v[4], c[4];
        #pragma unroll
        for (int e = 0; e < 4; e++) v[e] = __builtin_nontemporal_load(sim + e * 64 + lane);
        #pragma unroll
        for (int e = 0; e < 4; e++) c[e] = __builtin_nontemporal_load(coef + e * 64 + lane);

        float se = 0.0f, diag = 0.0f, sw = 0.0f, sws = 0.0f;
        #pragma unroll
        for (int e = 0; e < 4; e++) {
            #pragma unroll
            for (int q = 0; q < 4; q++) {
                float s  = v[e][q] * INV_TEMP;
                float es = __expf(s);
                se += es;
                if (e * 256 + lane * 4 + q == j) diag = es;
                float cw = c[e][q];
                float w = cw > 0.0f ? cw : 0.0f;
                sw  += w;
                sws += w * s;
            }
        }
        #pragma unroll
        for (int off = 32; off; off >>= 1) {
            se   += __shfl_xor(se,   off);
            diag += __shfl_xor(diag, off);
            sw   += __shfl_xor(sw,   off);
            sws  += __shfl_xor(sws,  off);
        }
        float logden = logf(se - diag + EPSF);
        bool hp = sw > 0.0f;
        float loss = (logden * sw - sws) / (sw + EPSF);
        float (*part)[2] = (float(*)[2])As;
        if (lane == 0) {
            part[wv][0] = hp ? loss : 0.0f;
            part[wv][1] = hp ? 1.0f : 0.0f;
        }
        __syncthreads();
        if (tid == 0) {
            ws[WS_CONTR + cidx * 2 + 0] = part[0][0] + part[1][0] + part[2][0] + part[3][0];
            ws[WS_CONTR + cidx * 2 + 1] = part[0][1] + part[1][1] + part[2][1] + part[3][1];
        }
        return;
    }

    if (r < 12) {
        // ---------------- den: 64x64 bf16 MFMA tile, acc[2][2] ---------------
        int b   = bid & 7;                 // XCD affinity
        int idx = g >> 1;                  // 0..255 (parity of g covers all b)
        int lt  = idx >> 4, tt = idx & 15;
        int l0  = lt * 64,  t0 = tt * 64;
        int wr  = wv >> 1,  wc = wv & 1;

        int srow = tid >> 2;               // 0..63
        int sq   = tid & 3;                // 8-float quarter
        const float* gA = box + ((size_t)b * LL + l0 + srow) * DD + sq * 8;
        const float* gB = tag + ((size_t)b * LL + t0 + srow) * DD + sq * 8;
        short* wA = &As[srow * ST + sq * 8];
        short* wB = &Bs[srow * ST + sq * 8];

        f32x4 acc[2][2];
        #pragma unroll
        for (int m = 0; m < 2; m++)
            #pragma unroll
            for (int n = 0; n < 2; n++) acc[m][n] = (f32x4){0.f, 0.f, 0.f, 0.f};

        const short* rA = &As[(wr * 32 + (lane & 15)) * ST + (lane >> 4) * 8];
        const short* rB = &Bs[(wc * 32 + (lane & 15)) * ST + (lane >> 4) * 8];

        for (int d0 = 0; d0 < DD; d0 += 32) {
            __syncthreads();
            float4 fa0 = *(const float4*)(gA + d0);
            float4 fa1 = *(const float4*)(gA + d0 + 4);
            float4 fb0 = *(const float4*)(gB + d0);
            float4 fb1 = *(const float4*)(gB + d0 + 4);
            short8 va = {bfb(fa0.x), bfb(fa0.y), bfb(fa0.z), bfb(fa0.w),
                         bfb(fa1.x), bfb(fa1.y), bfb(fa1.z), bfb(fa1.w)};
            short8 vb = {bfb(fb0.x), bfb(fb0.y), bfb(fb0.z), bfb(fb0.w),
                         bfb(fb1.x), bfb(fb1.y), bfb(fb1.z), bfb(fb1.w)};
            *(short8*)wA = va;
            *(short8*)wB = vb;
            __syncthreads();

            short8 af0 = *(const short8*)rA;
            short8 af1 = *(const short8*)(rA + 16 * ST);
            short8 bf0 = *(const short8*)rB;
            short8 bf1 = *(const short8*)(rB + 16 * ST);
            acc[0][0] = __builtin_amdgcn_mfma_f32_16x16x32_bf16(af0, bf0, acc[0][0], 0, 0, 0);
            acc[0][1] = __builtin_amdgcn_mfma_f32_16x16x32_bf16(af0, bf1, acc[0][1], 0, 0, 0);
            acc[1][0] = __builtin_amdgcn_mfma_f32_16x16x32_bf16(af1, bf0, acc[1][0], 0, 0, 0);
            acc[1][1] = __builtin_amdgcn_mfma_f32_16x16x32_bf16(af1, bf1, acc[1][1], 0, 0, 0);
        }

        int mode = mask_mode(att_raw);
        bool mk[2];
        #pragma unroll
        for (int n = 0; n < 2; n++) {
            int t = t0 + wc * 32 + n * 16 + (lane & 15);
            mk[n] = get_mask(dtm_raw, b * (2 * LL) + LL + t, mode);
        }
        __syncthreads();                   // done reading As/Bs
        float* part = (float*)As;          // [64][2]
        #pragma unroll
        for (int m = 0; m < 2; m++) {
            #pragma unroll
            for (int reg = 0; reg < 4; reg++) {
                float s = (mk[0] ? __expf(acc[m][0][reg] * INV_TEMP) : 0.0f)
                        + (mk[1] ? __expf(acc[m][1][reg] * INV_TEMP) : 0.0f);
                #pragma unroll
                for (int off = 1; off < 16; off <<= 1) s += __shfl_xor(s, off);
                if ((lane & 15) == 0) {
                    int rl = wr * 32 + m * 16 + (lane >> 4) * 4 + reg;
                    part[rl * 2 + wc] = s;
                }
            }
        }
        __syncthreads();
        if (tid < 64) {
            float s = part[tid * 2] + part[tid * 2 + 1];
            ws[WS_DENP + ((size_t)b * LL + l0 + tid) * 16 + tt] = s;
        }
        return;
    }

    if (r < 16) {
        // ---------------- ptr + empty (XCD-pinned) ---------------------------
        int b  = bid & 7;
        int li = g >> 1;                   // 0..255
        int i  = li * 4 + wv;
        int row = b * LL + i;
        int mode = mask_mode(att_raw);

        const float4* tp = (const float4*)(tag + (size_t)row * DD + lane * 8);
        const float4* ep = (const float4*)(emptyp + (size_t)b * DD + lane * 8);
        float4 t0v = tp[0], t1v = tp[1];
        float4 e0  = ep[0], e1  = ep[1];
        float de = e0.x * t0v.x + e0.y * t0v.y + e0.z * t0v.z + e0.w * t0v.w
                 + e1.x * t1v.x + e1.y * t1v.y + e1.z * t1v.z + e1.w * t1v.w;

        const float4* bp = (const float4*)(box + (size_t)row * DD + lane * 8);
        float4 x0 = bp[0], x1 = bp[1];
        float4 ya0 = {0.f,0.f,0.f,0.f}, ya1 = {0.f,0.f,0.f,0.f};
        float cnt = 0.0f;
        bool running = true;
        for (int k = 0; k < KK; k++) {
            int idx = bidx[row * KK + k];
            running = running && (idx != -1);
            int rel  = idx - LL;
            int relc = min(max(rel, 0), LL - 1);
            bool dg = get_mask(dtm_raw, b * (2 * LL) + LL + relc, mode);
            if (running && dg) {
                const float4* gp = (const float4*)(tag + ((size_t)b * LL + relc) * DD + lane * 8);
                float4 y0 = gp[0], y1 = gp[1];
                ya0.x += y0.x; ya0.y += y0.y; ya0.z += y0.z; ya0.w += y0.w;
                ya1.x += y1.x; ya1.y += y1.y; ya1.z += y1.z; ya1.w += y1.w;
                cnt += 1.0f;
            }
        }
        float dsum = x0.x * ya0.x + x0.y * ya0.y + x0.z * ya0.z + x0.w * ya0.w
                   + x1.x * ya1.x + x1.y * ya1.y + x1.z * ya1.z + x1.w * ya1.w;
        #pragma unroll
        for (int off = 32; off; off >>= 1) {
            dsum += __shfl_xor(dsum, off);
            de   += __shfl_xor(de,   off);
        }
        if (lane == 0) {
            ws[WS_PTRROW + row * 2 + 0] = dsum;
            ws[WS_PTRROW + row * 2 + 1] = cnt;
        }
        bool att = get_mask(att_raw, b * (2 * LL) + LL + i, mode);
        float bce = 0.0f, acnt = 0.0f;
        if (att) {
            bool dtm = get_mask(dtm_raw, b * (2 * LL) + LL + i, mode);
            float tgt = dtm ? 0.0f : 1.0f;
            float sp  = fmaxf(de, 0.0f) + log1pf(expf(-fabsf(de)));
            bce = sp - de * tgt;
            acnt = 1.0f;
        }
        float (*part)[2] = (float(*)[2])As;
        if (lane == 0) { part[wv][0] = bce; part[wv][1] = acnt; }
        __syncthreads();
        if (tid == 0) {
            int slot = b * 256 + li;
            ws[WS_EMP + slot * 2 + 0] = part[0][0] + part[1][0] + part[2][0] + part[3][0];
            ws[WS_EMP + slot * 2 + 1] = part[0][1] + part[1][1] + part[2][1] + part[3][1];
        }
        return;
    }

    {
        // ---------------- cls: row softmax over V=64 -------------------------
        int cb  = g * 4 + (r - 16);        // 0..2047
        int row = cb * 4 + wv;
        float x  = logits[(size_t)row * VV + lane];
        float mx = wave_red_max(x);
        float se = wave_red_sum(__expf(x - mx));
        float sx = wave_red_sum(x);
        float logZ = mx + logf(se);
        int t = tok[row];
        float xt = __shfl(x, t);
        float per = 0.9f * (logZ - xt) + 0.1f * (logZ - sx * (1.0f / VV));
        bool valid = (t > 3);
        float (*part)[2] = (float(*)[2])As;
        if (lane == 0) {
            part[wv][0] = valid ? per : 0.0f;
            part[wv][1] = valid ? 1.0f : 0.0f;
        }
        __syncthreads();
        if (tid == 0) {
            ws[WS_CLS + cb * 2 + 0] = part[0][0] + part[1][0] + part[2][0] + part[3][0];
            ws[WS_CLS + cb * 2 + 1] = part[0][1] + part[1][1] + part[2][1] + part[3][1];
        }
    }
}

// ================= final combine: row log-coupling + tree reduce ============
// q: 0 cls_s,1 cls_c,2 ptr_s,3 ptr_c,4 row_s,5 row_c,6 col_s,7 col_c,
//    8 e0s,9 e0c,10 e1s,11 e1c
__global__ __launch_bounds__(1024) void k_final(const float* __restrict__ ws, float* __restrict__ out) {
    __shared__ float red[16][12];
    int tid  = threadIdx.x;
    int lane = tid & 63, wv = tid >> 6;

    float q[12];
    #pragma unroll
    for (int i = 0; i < 12; i++) q[i] = 0.0f;

    // ptr: per-row cnt*log(den) - 10*sumd, 8 rows per thread; den = sum of 16
    #pragma unroll
    for (int i = 0; i < 8; i++) {
        int row = tid * 8 + i;
        const float* dp = ws + WS_DENP + (size_t)row * 16;
        float den = 0.0f;
        #pragma unroll
        for (int p = 0; p < 4; p++) {
            float4 d = *(const float4*)(dp + p * 4);
            den += d.x + d.y + d.z + d.w;
        }
        float sumd = ws[WS_PTRROW + row * 2 + 0];
        float cnt  = ws[WS_PTRROW + row * 2 + 1];
        q[2] += cnt * logf(den + EPSF) - INV_TEMP * sumd;
        q[3] += cnt;
    }
    // cls: 2048 pairs
    #pragma unroll
    for (int it = 0; it < 2; it++) {
        int i = tid + it * 1024;
        q[0] += ws[WS_CLS + 2 * i];  q[1] += ws[WS_CLS + 2 * i + 1];
    }
    // contr: 4096 pairs; first 2048 row, last 2048 col
    q[4] = ws[WS_CONTR + 2 * tid]              + ws[WS_CONTR + 2 * (tid + 1024)];
    q[5] = ws[WS_CONTR + 2 * tid + 1]          + ws[WS_CONTR + 2 * (tid + 1024) + 1];
    q[6] = ws[WS_CONTR + 2 * (tid + 2048)]     + ws[WS_CONTR + 2 * (tid + 3072)];
    q[7] = ws[WS_CONTR + 2 * (tid + 2048) + 1] + ws[WS_CONTR + 2 * (tid + 3072) + 1];
    // empty: 2048 pairs; slot i has b = i>>8 (slot = b*256+li)
    q[8]  = ws[WS_EMP + 2 * tid];
    q[9]  = ws[WS_EMP + 2 * tid + 1];
    q[10] = ws[WS_EMP + 2 * (tid + 1024)];
    q[11] = ws[WS_EMP + 2 * (tid + 1024) + 1];

    #pragma unroll
    for (int i = 0; i < 12; i++) {
        #pragma unroll
        for (int off = 32; off; off >>= 1) q[i] += __shfl_xor(q[i], off);
    }
    if (lane == 0) {
        #pragma unroll
        for (int i = 0; i < 12; i++) red[wv][i] = q[i];
    }
    __syncthreads();
    if (tid == 0) {
        float s[8];
        #pragma unroll
        for (int i = 0; i < 8; i++) s[i] = 0.0f;
        float es[8], ec[8];
        #pragma unroll
        for (int i = 0; i < 8; i++) { es[i] = 0.0f; ec[i] = 0.0f; }
        #pragma unroll
        for (int w = 0; w < 16; w++) {
            #pragma unroll
            for (int i = 0; i < 8; i++) s[i] += red[w][i];
            es[(w >> 2)]     += red[w][8];
            ec[(w >> 2)]     += red[w][9];
            es[(w >> 2) + 4] += red[w][10];
            ec[(w >> 2) + 4] += red[w][11];
        }
        float cls = s[0] / fmaxf(s[1], 1.0f);
        float ptr = (s[3] > 0.0f) ? s[2] / fmaxf(s[3], 1.0f) : 0.0f;
        float emp = 0.0f;
        #pragma unroll
        for (int b = 0; b < 8; b++) emp += es[b] / fmaxf(ec[b], 1.0f);
        emp *= (1.0f / BB);
        float rc = (s[5] > 0.0f) ? s[4] / fmaxf(s[5], 1.0f) : 0.0f;
        float cc = (s[7] > 0.0f) ? s[6] / fmaxf(s[7], 1.0f) : 0.0f;
        float tot = cls + ptr + emp + 0.5f * (rc + cc);
        out[0] = tot; out[1] = cls; out[2] = ptr;
        out[3] = emp; out[4] = rc;  out[5] = cc;
    }
}

extern "C" void kernel_launch(void* const* d_in, const int* in_sizes, int n_in,
                              void* d_out, int out_size, void* d_ws, size_t ws_size,
                              hipStream_t stream) {
    (void)in_sizes; (void)n_in; (void)out_size; (void)ws_size;
    const int*   token_ids = (const int*)  d_in[0];
    const int*   box_idx   = (const int*)  d_in[1];
    const void*  dtm       =               d_in[2];
    const void*  att       =               d_in[3];
    const float* tag_log   = (const float*)d_in[4];
    const float* box_proj  = (const float*)d_in[5];
    const float* tag_proj  = (const float*)d_in[6];
    const float* empty_p   = (const float*)d_in[7];
    const float* row_sim   = (const float*)d_in[8];
    const float* col_sim   = (const float*)d_in[9];
    const float* row_coef  = (const float*)d_in[10];
    const float* col_coef  = (const float*)d_in[11];
    float* ws  = (float*)d_ws;
    float* out = (float*)d_out;

    // single interleaved launch: contr feeds the fabric while den (MFMA+L2)
    // and rest/cls (L2/VALU) ride the other pipes on every XCD concurrently.
    k_mega <<<512 * 20, 256, 0, stream>>>(box_proj, tag_proj, tag_log, token_ids,
                                          box_idx, empty_p, row_sim, col_sim,
                                          row_coef, col_coef, dtm, att, ws);
    k_final<<<1, 1024, 0, stream>>>(ws, out);
}

// Round 14
// 60.654 us; speedup vs baseline: 1.3475x; 1.3475x over previous
//
#include <hip/hip_runtime.h>
#include <hip/hip_bf16.h>
#include <math.h>

#define BB 8
#define LL 1024
#define DD 512
#define VV 64
#define KK 8

constexpr float INV_TEMP = 10.0f;   // 1/TEMP
constexpr float EPSF     = 1e-10f;

// ---------------- workspace float layout (NO atomics, NO memset) ------------
#define WS_DENP   0                        // den partials [8192][16]
#define WS_CLS    (8192*16)                // cls  {sum,cnt} x 2048
#define WS_EMP    (WS_CLS + 4096)          // emp  {sum,cnt} x 2048, slot = b*256+li
#define WS_CONTR  (WS_EMP + 4096)          // contr {sum,cnt} x 4096 (mat0:[0,2048))
#define WS_PTRROW (WS_CONTR + 8192)        // ptr per-row {sumd,cnt} x 8192
#define WS_FIN    (WS_PTRROW + 16384)      // stage-1 partials: 64 blocks x 10

typedef __attribute__((ext_vector_type(8))) short  short8;
typedef __attribute__((ext_vector_type(4))) float  f32x4;

// ---------------- bool-dtype detection ----------------
// MUST be fed attention_mask: its first L entries are all-True by construction.
__device__ __forceinline__ int mask_mode(const void* att_raw) {
    const unsigned* w = (const unsigned*)att_raw;
    unsigned w0 = w[0];
    if (w0 == 0x01010101u) return 0;           // bool/uint8
    if (w0 == 0x3f800000u) return 2;           // float32
    if (w0 == 1u) return (w[1] == 0u) ? 3 : 1; // int64 : int32
    return 0;
}
__device__ __forceinline__ bool get_mask(const void* p, int idx, int mode) {
    if (mode == 0) return ((const unsigned char*)p)[idx] != 0;
    if (mode == 1) return ((const int*)p)[idx] != 0;
    if (mode == 3) return ((const unsigned*)p)[2*idx] != 0u;
    return ((const float*)p)[idx] != 0.0f;
}

__device__ __forceinline__ float wave_red_sum(float v) {
    #pragma unroll
    for (int off = 32; off; off >>= 1) v += __shfl_xor(v, off);
    return v;
}
__device__ __forceinline__ float wave_red_max(float v) {
    #pragma unroll
    for (int off = 32; off; off >>= 1) v = fmaxf(v, __shfl_xor(v, off));
    return v;
}

__device__ __forceinline__ short bfb(float f) {
    __hip_bfloat16 h = __float2bfloat16(f);
    union { __hip_bfloat16 h; short u; } c; c.h = h; return c.u;
}

#define ST 40            // LDS row stride in shorts (80 bytes)

// ================= mega: contr x8 | den x4 | rest x4 | cls x4 per group ======
// (unchanged from round 13 — 63.9us, overlap verified)
__global__ __launch_bounds__(256, 8) void k_mega(
        const float* __restrict__ box,     const float* __restrict__ tag,
        const float* __restrict__ logits,  const int* __restrict__ tok,
        const int* __restrict__ bidx,      const float* __restrict__ emptyp,
        const float* __restrict__ row_sim, const float* __restrict__ col_sim,
        const float* __restrict__ row_coef,const float* __restrict__ col_coef,
        const void* __restrict__ dtm_raw,  const void* __restrict__ att_raw,
        float* __restrict__ ws) {
    __shared__ short As[64 * ST];
    __shared__ short Bs[64 * ST];

    int bid = blockIdx.x;
    int g   = bid / 20;
    int r   = bid - g * 20;
    int tid  = threadIdx.x;
    int lane = tid & 63;
    int wv   = tid >> 6;

    if (r < 8) {
        // ---------------- span contrastive (nt loads, shift-invariant) -------
        int cidx = g * 8 + r;              // 0..4095
        int gw   = cidx * 4 + wv;
        int mat  = gw >> 13;
        int row  = gw & 8191;
        int j    = row & 1023;
        const f32x4* sim  = (const f32x4*)((mat ? col_sim  : row_sim)  + (size_t)row * LL);
        const f32x4* coef = (const f32x4*)((mat ? col_coef : row_coef) + (size_t)row * LL);

        f32x4 v[4], c[4];
        #pragma unroll
        for (int e = 0; e < 4; e++) v[e] = __builtin_nontemporal_load(sim + e * 64 + lane);
        #pragma unroll
        for (int e = 0; e < 4; e++) c[e] = __builtin_nontemporal_load(coef + e * 64 + lane);

        float se = 0.0f, diag = 0.0f, sw = 0.0f, sws = 0.0f;
        #pragma unroll
        for (int e = 0; e < 4; e++) {
            #pragma unroll
            for (int q = 0; q < 4; q++) {
                float s  = v[e][q] * INV_TEMP;
                float es = __expf(s);
                se += es;
                if (e * 256 + lane * 4 + q == j) diag = es;
                float cw = c[e][q];
                float w = cw > 0.0f ? cw : 0.0f;
                sw  += w;
                sws += w * s;
            }
        }
        #pragma unroll
        for (int off = 32; off; off >>= 1) {
            se   += __shfl_xor(se,   off);
            diag += __shfl_xor(diag, off);
            sw   += __shfl_xor(sw,   off);
            sws  += __shfl_xor(sws,  off);
        }
        float logden = logf(se - diag + EPSF);
        bool hp = sw > 0.0f;
        float loss = (logden * sw - sws) / (sw + EPSF);
        float (*part)[2] = (float(*)[2])As;
        if (lane == 0) {
            part[wv][0] = hp ? loss : 0.0f;
            part[wv][1] = hp ? 1.0f : 0.0f;
        }
        __syncthreads();
        if (tid == 0) {
            ws[WS_CONTR + cidx * 2 + 0] = part[0][0] + part[1][0] + part[2][0] + part[3][0];
            ws[WS_CONTR + cidx * 2 + 1] = part[0][1] + part[1][1] + part[2][1] + part[3][1];
        }
        return;
    }

    if (r < 12) {
        // ---------------- den: 64x64 bf16 MFMA tile, acc[2][2] ---------------
        int b   = bid & 7;                 // XCD affinity
        int idx = g >> 1;                  // 0..255 (parity of g covers all b)
        int lt  = idx >> 4, tt = idx & 15;
        int l0  = lt * 64,  t0 = tt * 64;
        int wr  = wv >> 1,  wc = wv & 1;

        int srow = tid >> 2;               // 0..63
        int sq   = tid & 3;                // 8-float quarter
        const float* gA = box + ((size_t)b * LL + l0 + srow) * DD + sq * 8;
        const float* gB = tag + ((size_t)b * LL + t0 + srow) * DD + sq * 8;
        short* wA = &As[srow * ST + sq * 8];
        short* wB = &Bs[srow * ST + sq * 8];

        f32x4 acc[2][2];
        #pragma unroll
        for (int m = 0; m < 2; m++)
            #pragma unroll
            for (int n = 0; n < 2; n++) acc[m][n] = (f32x4){0.f, 0.f, 0.f, 0.f};

        const short* rA = &As[(wr * 32 + (lane & 15)) * ST + (lane >> 4) * 8];
        const short* rB = &Bs[(wc * 32 + (lane & 15)) * ST + (lane >> 4) * 8];

        for (int d0 = 0; d0 < DD; d0 += 32) {
            __syncthreads();
            float4 fa0 = *(const float4*)(gA + d0);
            float4 fa1 = *(const float4*)(gA + d0 + 4);
            float4 fb0 = *(const float4*)(gB + d0);
            float4 fb1 = *(const float4*)(gB + d0 + 4);
            short8 va = {bfb(fa0.x), bfb(fa0.y), bfb(fa0.z), bfb(fa0.w),
                         bfb(fa1.x), bfb(fa1.y), bfb(fa1.z), bfb(fa1.w)};
            short8 vb = {bfb(fb0.x), bfb(fb0.y), bfb(fb0.z), bfb(fb0.w),
                         bfb(fb1.x), bfb(fb1.y), bfb(fb1.z), bfb(fb1.w)};
            *(short8*)wA = va;
            *(short8*)wB = vb;
            __syncthreads();

            short8 af0 = *(const short8*)rA;
            short8 af1 = *(const short8*)(rA + 16 * ST);
            short8 bf0 = *(const short8*)rB;
            short8 bf1 = *(const short8*)(rB + 16 * ST);
            acc[0][0] = __builtin_amdgcn_mfma_f32_16x16x32_bf16(af0, bf0, acc[0][0], 0, 0, 0);
            acc[0][1] = __builtin_amdgcn_mfma_f32_16x16x32_bf16(af0, bf1, acc[0][1], 0, 0, 0);
            acc[1][0] = __builtin_amdgcn_mfma_f32_16x16x32_bf16(af1, bf0, acc[1][0], 0, 0, 0);
            acc[1][1] = __builtin_amdgcn_mfma_f32_16x16x32_bf16(af1, bf1, acc[1][1], 0, 0, 0);
        }

        int mode = mask_mode(att_raw);
        bool mk[2];
        #pragma unroll
        for (int n = 0; n < 2; n++) {
            int t = t0 + wc * 32 + n * 16 + (lane & 15);
            mk[n] = get_mask(dtm_raw, b * (2 * LL) + LL + t, mode);
        }
        __syncthreads();                   // done reading As/Bs
        float* part = (float*)As;          // [64][2]
        #pragma unroll
        for (int m = 0; m < 2; m++) {
            #pragma unroll
            for (int reg = 0; reg < 4; reg++) {
                float s = (mk[0] ? __expf(acc[m][0][reg] * INV_TEMP) : 0.0f)
                        + (mk[1] ? __expf(acc[m][1][reg] * INV_TEMP) : 0.0f);
                #pragma unroll
                for (int off = 1; off < 16; off <<= 1) s += __shfl_xor(s, off);
                if ((lane & 15) == 0) {
                    int rl = wr * 32 + m * 16 + (lane >> 4) * 4 + reg;
                    part[rl * 2 + wc] = s;
                }
            }
        }
        __syncthreads();
        if (tid < 64) {
            float s = part[tid * 2] + part[tid * 2 + 1];
            ws[WS_DENP + ((size_t)b * LL + l0 + tid) * 16 + tt] = s;
        }
        return;
    }

    if (r < 16) {
        // ---------------- ptr + empty (XCD-pinned) ---------------------------
        int b  = bid & 7;
        int li = g >> 1;                   // 0..255
        int i  = li * 4 + wv;
        int row = b * LL + i;
        int mode = mask_mode(att_raw);

        const float4* tp = (const float4*)(tag + (size_t)row * DD + lane * 8);
        const float4* ep = (const float4*)(emptyp + (size_t)b * DD + lane * 8);
        float4 t0v = tp[0], t1v = tp[1];
        float4 e0  = ep[0], e1  = ep[1];
        float de = e0.x * t0v.x + e0.y * t0v.y + e0.z * t0v.z + e0.w * t0v.w
                 + e1.x * t1v.x + e1.y * t1v.y + e1.z * t1v.z + e1.w * t1v.w;

        const float4* bp = (const float4*)(box + (size_t)row * DD + lane * 8);
        float4 x0 = bp[0], x1 = bp[1];
        float4 ya0 = {0.f,0.f,0.f,0.f}, ya1 = {0.f,0.f,0.f,0.f};
        float cnt = 0.0f;
        bool running = true;
        for (int k = 0; k < KK; k++) {
            int idx = bidx[row * KK + k];
            running = running && (idx != -1);
            int rel  = idx - LL;
            int relc = min(max(rel, 0), LL - 1);
            bool dg = get_mask(dtm_raw, b * (2 * LL) + LL + relc, mode);
            if (running && dg) {
                const float4* gp = (const float4*)(tag + ((size_t)b * LL + relc) * DD + lane * 8);
                float4 y0 = gp[0], y1 = gp[1];
                ya0.x += y0.x; ya0.y += y0.y; ya0.z += y0.z; ya0.w += y0.w;
                ya1.x += y1.x; ya1.y += y1.y; ya1.z += y1.z; ya1.w += y1.w;
                cnt += 1.0f;
            }
        }
        float dsum = x0.x * ya0.x + x0.y * ya0.y + x0.z * ya0.z + x0.w * ya0.w
                   + x1.x * ya1.x + x1.y * ya1.y + x1.z * ya1.z + x1.w * ya1.w;
        #pragma unroll
        for (int off = 32; off; off >>= 1) {
            dsum += __shfl_xor(dsum, off);
            de   += __shfl_xor(de,   off);
        }
        if (lane == 0) {
            ws[WS_PTRROW + row * 2 + 0] = dsum;
            ws[WS_PTRROW + row * 2 + 1] = cnt;
        }
        bool att = get_mask(att_raw, b * (2 * LL) + LL + i, mode);
        float bce = 0.0f, acnt = 0.0f;
        if (att) {
            bool dtm = get_mask(dtm_raw, b * (2 * LL) + LL + i, mode);
            float tgt = dtm ? 0.0f : 1.0f;
            float sp  = fmaxf(de, 0.0f) + log1pf(expf(-fabsf(de)));
            bce = sp - de * tgt;
            acnt = 1.0f;
        }
        float (*part)[2] = (float(*)[2])As;
        if (lane == 0) { part[wv][0] = bce; part[wv][1] = acnt; }
        __syncthreads();
        if (tid == 0) {
            int slot = b * 256 + li;
            ws[WS_EMP + slot * 2 + 0] = part[0][0] + part[1][0] + part[2][0] + part[3][0];
            ws[WS_EMP + slot * 2 + 1] = part[0][1] + part[1][1] + part[2][1] + part[3][1];
        }
        return;
    }

    {
        // ---------------- cls: row softmax over V=64 -------------------------
        int cb  = g * 4 + (r - 16);        // 0..2047
        int row = cb * 4 + wv;
        float x  = logits[(size_t)row * VV + lane];
        float mx = wave_red_max(x);
        float se = wave_red_sum(__expf(x - mx));
        float sx = wave_red_sum(x);
        float logZ = mx + logf(se);
        int t = tok[row];
        float xt = __shfl(x, t);
        float per = 0.9f * (logZ - xt) + 0.1f * (logZ - sx * (1.0f / VV));
        bool valid = (t > 3);
        float (*part)[2] = (float(*)[2])As;
        if (lane == 0) {
            part[wv][0] = valid ? per : 0.0f;
            part[wv][1] = valid ? 1.0f : 0.0f;
        }
        __syncthreads();
        if (tid == 0) {
            ws[WS_CLS + cb * 2 + 0] = part[0][0] + part[1][0] + part[2][0] + part[3][0];
            ws[WS_CLS + cb * 2 + 1] = part[0][1] + part[1][1] + part[2][1] + part[3][1];
        }
    }
}

// ========== final stage 1: 64 blocks, parallel partial reduction ============
// per-block output (WS_FIN + bid*10):
//   0 cls_s, 1 cls_c, 2 ptr_s, 3 ptr_c, 4 row_s, 5 row_c, 6 col_s, 7 col_c,
//   8 emp_s, 9 emp_c  (block bid covers emp slots [bid*32,bid*32+32) -> one b)
__global__ __launch_bounds__(256) void k_final1(float* __restrict__ ws) {
    __shared__ float red[4][10];
    int bid  = blockIdx.x;     // 0..63
    int tid  = threadIdx.x;
    int lane = tid & 63, wv = tid >> 6;

    float q[10];
    #pragma unroll
    for (int i = 0; i < 10; i++) q[i] = 0.0f;

    // ptr: 128 rows per block (threads 0..127, one row each)
    if (tid < 128) {
        int row = bid * 128 + tid;
        const float* dp = ws + WS_DENP + (size_t)row * 16;
        float den = 0.0f;
        #pragma unroll
        for (int p = 0; p < 4; p++) {
            float4 d = *(const float4*)(dp + p * 4);
            den += d.x + d.y + d.z + d.w;
        }
        float sumd = ws[WS_PTRROW + row * 2 + 0];
        float cnt  = ws[WS_PTRROW + row * 2 + 1];
        q[2] = cnt * logf(den + EPSF) - INV_TEMP * sumd;
        q[3] = cnt;
    }
    // cls: 32 pairs per block
    if (tid < 32) {
        int p = bid * 32 + tid;
        q[0] = ws[WS_CLS + 2 * p];
        q[1] = ws[WS_CLS + 2 * p + 1];
    }
    // contr: 64 pairs per block; bid<32 -> mat0, bid>=32 -> mat1 (2048/64=32)
    if (tid < 64) {
        int p = bid * 64 + tid;
        float s = ws[WS_CONTR + 2 * p], c = ws[WS_CONTR + 2 * p + 1];
        if (p < 2048) { q[4] = s; q[5] = c; }
        else          { q[6] = s; q[7] = c; }
    }
    // emp: 32 pairs per block (all same b = bid>>3)
    if (tid < 32) {
        int p = bid * 32 + tid;
        q[8] = ws[WS_EMP + 2 * p];
        q[9] = ws[WS_EMP + 2 * p + 1];
    }

    #pragma unroll
    for (int i = 0; i < 10; i++) {
        #pragma unroll
        for (int off = 32; off; off >>= 1) q[i] += __shfl_xor(q[i], off);
    }
    if (lane == 0) {
        #pragma unroll
        for (int i = 0; i < 10; i++) red[wv][i] = q[i];
    }
    __syncthreads();
    if (tid == 0) {
        #pragma unroll
        for (int i = 0; i < 10; i++)
            ws[WS_FIN + bid * 10 + i] = red[0][i] + red[1][i] + red[2][i] + red[3][i];
    }
}

// ========== final stage 2: 1 block x 64 lanes, combine 64 partials ==========
__global__ void k_final2(const float* __restrict__ ws, float* __restrict__ out) {
    int lane = threadIdx.x & 63;
    float v[10];
    #pragma unroll
    for (int i = 0; i < 10; i++) v[i] = ws[WS_FIN + lane * 10 + i];

    float s[8];
    #pragma unroll
    for (int i = 0; i < 8; i++) {
        s[i] = v[i];
        #pragma unroll
        for (int off = 32; off; off >>= 1) s[i] += __shfl_xor(s[i], off);
    }
    // empty: lane w holds b = w>>3; reduce within 8-lane groups, then ratios
    float es = v[8], ec = v[9];
    es += __shfl_xor(es, 1); ec += __shfl_xor(ec, 1);
    es += __shfl_xor(es, 2); ec += __shfl_xor(ec, 2);
    es += __shfl_xor(es, 4); ec += __shfl_xor(ec, 4);
    float ratio = ((lane & 7) == 0) ? es / fmaxf(ec, 1.0f) : 0.0f;
    ratio += __shfl_xor(ratio, 8);
    ratio += __shfl_xor(ratio, 16);
    ratio += __shfl_xor(ratio, 32);

    if (lane == 0) {
        float cls = s[0] / fmaxf(s[1], 1.0f);
        float ptr = (s[3] > 0.0f) ? s[2] / fmaxf(s[3], 1.0f) : 0.0f;
        float emp = ratio * (1.0f / BB);
        float rc = (s[5] > 0.0f) ? s[4] / fmaxf(s[5], 1.0f) : 0.0f;
        float cc = (s[7] > 0.0f) ? s[6] / fmaxf(s[7], 1.0f) : 0.0f;
        float tot = cls + ptr + emp + 0.5f * (rc + cc);
        out[0] = tot; out[1] = cls; out[2] = ptr;
        out[3] = emp; out[4] = rc;  out[5] = cc;
    }
}

extern "C" void kernel_launch(void* const* d_in, const int* in_sizes, int n_in,
                              void* d_out, int out_size, void* d_ws, size_t ws_size,
                              hipStream_t stream) {
    (void)in_sizes; (void)n_in; (void)out_size; (void)ws_size;
    const int*   token_ids = (const int*)  d_in[0];
    const int*   box_idx   = (const int*)  d_in[1];
    const void*  dtm       =               d_in[2];
    const void*  att       =               d_in[3];
    const float* tag_log   = (const float*)d_in[4];
    const float* box_proj  = (const float*)d_in[5];
    const float* tag_proj  = (const float*)d_in[6];
    const float* empty_p   = (const float*)d_in[7];
    const float* row_sim   = (const float*)d_in[8];
    const float* col_sim   = (const float*)d_in[9];
    const float* row_coef  = (const float*)d_in[10];
    const float* col_coef  = (const float*)d_in[11];
    float* ws  = (float*)d_ws;
    float* out = (float*)d_out;

    // single interleaved launch (overlap verified r13), then 2-stage combine
    k_mega  <<<512 * 20, 256, 0, stream>>>(box_proj, tag_proj, tag_log, token_ids,
                                           box_idx, empty_p, row_sim, col_sim,
                                           row_coef, col_coef, dtm, att, ws);
    k_final1<<<64, 256, 0, stream>>>(ws);
    k_final2<<<1, 64, 0, stream>>>(ws, out);
}